// Round 17
// baseline (1462.124 us; speedup 1.0000x reference)
//
#include <hip/hip_runtime.h>
#include <hip/hip_bf16.h>
#include <stdint.h>

#define MDIM 16384   // B*S = 4*4096
#define NDIM 2048    // MAX_OUT
#define KDIM 2048    // MAX_IN

typedef __attribute__((ext_vector_type(4))) float f32x4;
typedef __attribute__((ext_vector_type(8))) short s16x8;

__device__ __forceinline__ void gload_lds16(const __hip_bfloat16* g, void* l) {
    __builtin_amdgcn_global_load_lds(
        (const __attribute__((address_space(1))) void*)g,
        (__attribute__((address_space(3))) void*)l,
        16, 0, 0);
}

// ---------------- fused prep kernel (one launch, three block ranges) --------
#define XBLKS 16384
#define WBLKS 2048

__global__ __launch_bounds__(256) void prep_all(
    const float* __restrict__ x, const float* __restrict__ weights,
    const float* __restrict__ W, const float* __restrict__ b,
    const float* __restrict__ a_scales, const float* __restrict__ w_scales,
    __hip_bfloat16* __restrict__ xq, __hip_bfloat16* __restrict__ wq,
    float* __restrict__ bm)
{
    const int blk = blockIdx.x;
    if (blk < XBLKS) {
        float A0 = 0.f, A1 = 0.f;
        #pragma unroll
        for (int k = 0; k < 16; ++k) {
            float w = weights[k];
            if (((k >> 1) & 1) == 0) A0 += w; else A1 += w;
        }
        const float s0 = a_scales[0], s1 = a_scales[1];
        const float r0 = 1.f / s0, r1 = 1.f / s1;

        size_t idx = ((size_t)blk * 256 + threadIdx.x) * 8;
        const f32x4* xv = (const f32x4*)(x + idx);
        f32x4 v0 = xv[0], v1 = xv[1];
        float vals[8] = {v0.x, v0.y, v0.z, v0.w, v1.x, v1.y, v1.z, v1.w};

        union { s16x8 v; __hip_bfloat16 h[8]; } u;
        #pragma unroll
        for (int j = 0; j < 8; ++j) {
            float q0 = rintf(fminf(fmaxf(vals[j] * r0, -8.f),   7.f)) * s0;
            float q1 = rintf(fminf(fmaxf(vals[j] * r1, -128.f), 127.f)) * s1;
            u.h[j] = __float2bfloat16(A0 * q0 + A1 * q1);
        }
        *(s16x8*)(xq + idx) = u.v;
    } else if (blk < XBLKS + WBLKS) {
        float c00 = weights[0] + weights[2]  + weights[4]  + weights[6];
        float c01 = weights[1] + weights[3]  + weights[5]  + weights[7];
        float c10 = weights[8] + weights[10] + weights[12] + weights[14];
        float c11 = weights[9] + weights[11] + weights[13] + weights[15];

        const float s0 = w_scales[0], s1 = w_scales[1];
        const float r0 = 1.f / s0, r1 = 1.f / s1;

        size_t idx = ((size_t)(blk - XBLKS) * 256 + threadIdx.x) * 8;
        const int o = (int)(idx >> 11);
        const int c = (int)(idx & 2047);
        const bool inner = (o < 1024) && (c < 1024);
        const float k0 = inner ? (c00 + c10) : c10;
        const float k1 = inner ? (c01 + c11) : c11;

        const f32x4* wv = (const f32x4*)(W + idx);
        f32x4 v0 = wv[0], v1 = wv[1];
        float vals[8] = {v0.x, v0.y, v0.z, v0.w, v1.x, v1.y, v1.z, v1.w};

        union { s16x8 v; __hip_bfloat16 h[8]; } u;
        #pragma unroll
        for (int j = 0; j < 8; ++j) {
            float q0 = rintf(fminf(fmaxf(vals[j] * r0, -8.f),   7.f)) * s0;
            float q1 = rintf(fminf(fmaxf(vals[j] * r1, -128.f), 127.f)) * s1;
            u.h[j] = __float2bfloat16(k0 * q0 + k1 * q1);
        }
        *(s16x8*)(wq + idx) = u.v;
    } else {
        int o = (blk - XBLKS - WBLKS) * 256 + threadIdx.x;
        if (o < NDIM) {
            float S1 = 0.f, S0 = 0.f;
            #pragma unroll
            for (int k = 0; k < 8; ++k)  S0 += weights[k];
            #pragma unroll
            for (int k = 8; k < 16; ++k) S1 += weights[k];
            bm[o] = b[o] * ((o < 1024) ? (S0 + S1) : S1);
        }
    }
}

// ---------------- GEMM: 256x256 tile, 8 waves, RING-2 dbuf (64 KiB) ->
// TWO blocks co-resident per CU (launch_bounds(512,4): 16 waves/CU).
// Rationale: the K-loop already runs at ~1700 cyc/chunk (near the verified
// m201 level); the exposed cost is the ~30us serial C-write tail per block
// (WRITE_SIZE 131 MB). Co-residency overlaps block A's epilogue/vmcnt-drain
// with block B's MFMAs (m114 mechanism). Chunk body = champion R7 form;
// ring-2 forces vmcnt(0)/chunk (m97-style) -- covered by the sibling block.
// Tile geometry, T1, T2 swizzles unchanged (R10's failure modes avoided). --

#define NCH 64           // K chunks of 32
#define ASLOT 16384      // bytes per slot plane (256 rows x 64 B)
#define BREG  32768      // B region base (2 A slots first); total 65536 B

#define MFMA(a, b, c) __builtin_amdgcn_mfma_f32_16x16x32_bf16((a), (b), (c), 0, 0, 0)

// Compute chunk c from slot S; stage chunk c+1 into slot S^1.
#define CHUNK(S)                                                             \
  {                                                                          \
    asm volatile("" ::: "memory");  /* no hoist of reads above barrier */    \
    s16x8 af[8], bf[4];                                                      \
    _Pragma("unroll")                                                        \
    for (int m_ = 0; m_ < 8; ++m_)                                           \
      af[m_] = *(const s16x8*)(lds + (S) * ASLOT + aoff + m_ * 1024);        \
    _Pragma("unroll")                                                        \
    for (int n_ = 0; n_ < 4; ++n_)                                           \
      bf[n_] = *(const s16x8*)(lds + BREG + (S) * ASLOT + boff + n_ * 1024); \
    gload_lds16(As0 + kg * 32, lds + ((S) ^ 1) * ASLOT + ldoff);             \
    gload_lds16(As1 + kg * 32, lds + ((S) ^ 1) * ASLOT + 8192 + ldoff);      \
    gload_lds16(Bs0 + kg * 32, lds + BREG + ((S) ^ 1) * ASLOT + ldoff);      \
    gload_lds16(Bs1 + kg * 32, lds + BREG + ((S) ^ 1) * ASLOT + 8192 + ldoff); \
    kg = (kg + 1) & (NCH - 1);                                               \
    __builtin_amdgcn_s_setprio(1);                                           \
    _Pragma("unroll")                                                        \
    for (int m_ = 0; m_ < 8; ++m_) {                                         \
      acc[m_][0] = MFMA(af[m_], bf[0], acc[m_][0]);                          \
      acc[m_][1] = MFMA(af[m_], bf[1], acc[m_][1]);                          \
      acc[m_][2] = MFMA(af[m_], bf[2], acc[m_][2]);                          \
      acc[m_][3] = MFMA(af[m_], bf[3], acc[m_][3]);                          \
    }                                                                        \
    __builtin_amdgcn_s_setprio(0);                                           \
    asm volatile("s_waitcnt vmcnt(0)" ::: "memory");  /* c+1 landed */       \
    __builtin_amdgcn_s_barrier();                                            \
  }

__global__ __launch_bounds__(512, 4) void gemm256(
    const __hip_bfloat16* __restrict__ A,
    const __hip_bfloat16* __restrict__ B,
    const float* __restrict__ bias,
    float* __restrict__ C)
{
    __shared__ char lds[4 * ASLOT];   // 65536 B -> 2 blocks/CU

    const int tid  = threadIdx.x;
    const int lane = tid & 63;
    const int wid  = tid >> 6;    // 0..7
    const int wm   = wid >> 2;    // 0..1  (M half)
    const int wn   = wid & 3;     // 0..3  (N quarter)

    // T1 (measured FETCH ~104 MB): XCD = bid%8 owns 8 row-panels x 8 cols.
    const int bid  = blockIdx.x;
    const int swz  = (bid & 7) * 64 + (bid >> 3);
    const int brow = (swz >> 3) * 256;
    const int bcol = (swz & 7) * 256;

    // ---- staging: linear LDS dest, pre-swizzled global source (T2) ----
    const int csw = (tid & 3) ^ ((tid >> 3) & 3);
    const __hip_bfloat16* As0 = A + (size_t)(brow + (tid >> 2)) * KDIM + csw * 8;
    const __hip_bfloat16* As1 = As0 + (size_t)128 * KDIM;
    const __hip_bfloat16* Bs0 = B + (size_t)(bcol + (tid >> 2)) * KDIM + csw * 8;
    const __hip_bfloat16* Bs1 = Bs0 + (size_t)128 * KDIM;
    const int ldoff = tid * 16;

    // ---- fragment-read constants (swizzle inverse; lane-constant XOR) ----
    const int fr  = lane & 15;
    const int l16 = lane >> 4;
    const int xr  = (l16 ^ ((fr >> 1) & 3)) * 16;
    const int aoff = (wm * 128 + fr) * 64 + xr;
    const int boff = (wn * 64  + fr) * 64 + xr;

    f32x4 acc[8][4];
    #pragma unroll
    for (int m = 0; m < 8; ++m)
        #pragma unroll
        for (int n = 0; n < 4; ++n)
            acc[m][n] = (f32x4){0.f, 0.f, 0.f, 0.f};

    int kg = 1;   // next chunk to stage

    // ---- prologue: stage chunk 0 -> slot 0; gate ----
    gload_lds16(As0, lds + ldoff);
    gload_lds16(As1, lds + 8192 + ldoff);
    gload_lds16(Bs0, lds + BREG + ldoff);
    gload_lds16(Bs1, lds + BREG + 8192 + ldoff);
    asm volatile("s_waitcnt vmcnt(0)" ::: "memory");
    __builtin_amdgcn_s_barrier();

    #pragma unroll 1
    for (int it = 0; it < NCH / 2; ++it) {
        CHUNK(0);   // chunk 2it   (stages 2it+1 -> slot 1)
        CHUNK(1);   // chunk 2it+1 (stages 2it+2 -> slot 0; last wraps dead)
    }
    asm volatile("s_waitcnt vmcnt(0) lgkmcnt(0)" ::: "memory");

    // ---- epilogue: C/D layout col = lane&15, row = (lane>>4)*4 + j ----
    const int ccol0 = bcol + wn * 64 + fr;
    const int crow0 = brow + wm * 128 + l16 * 4;
    float bv[4];
    #pragma unroll
    for (int n = 0; n < 4; ++n) bv[n] = bias[ccol0 + n * 16];

    #pragma unroll
    for (int m = 0; m < 8; ++m) {
        #pragma unroll
        for (int j = 0; j < 4; ++j) {
            float* Crow = C + (size_t)(crow0 + m * 16 + j) * NDIM;
            #pragma unroll
            for (int n = 0; n < 4; ++n)
                Crow[ccol0 + n * 16] = acc[m][n][j] + bv[n];
        }
    }
}

// ---------------- launcher ----------------

extern "C" void kernel_launch(void* const* d_in, const int* in_sizes, int n_in,
                              void* d_out, int out_size, void* d_ws, size_t ws_size,
                              hipStream_t stream) {
    const float* x        = (const float*)d_in[0];  // [4,4096,2048]
    const float* weights  = (const float*)d_in[1];  // [16]
    const float* W        = (const float*)d_in[2];  // [2048,2048]
    const float* b        = (const float*)d_in[3];  // [2048]
    const float* a_scales = (const float*)d_in[4];  // [2]
    const float* w_scales = (const float*)d_in[5];  // [2]
    float* out = (float*)d_out;

    __hip_bfloat16* xq = (__hip_bfloat16*)d_ws;                            // 67108864 B
    __hip_bfloat16* wq = (__hip_bfloat16*)((char*)d_ws + 67108864);        //  8388608 B
    float*          bm = (float*)((char*)d_ws + 67108864 + 8388608);       //     8192 B

    prep_all<<<dim3(XBLKS + WBLKS + 8), dim3(256), 0, stream>>>(
        x, weights, W, b, a_scales, w_scales, xq, wq, bm);
    gemm256<<<dim3((MDIM / 256) * (NDIM / 256)), dim3(512), 0, stream>>>(xq, wq, bm, out);
}

// Round 18
// 146.022 us; speedup vs baseline: 10.0130x; 10.0130x over previous
//
#include <hip/hip_runtime.h>
#include <hip/hip_bf16.h>
#include <stdint.h>

#define MDIM 16384   // B*S = 4*4096
#define NDIM 2048    // MAX_OUT
#define KDIM 2048    // MAX_IN

typedef __attribute__((ext_vector_type(4))) float f32x4;
typedef __attribute__((ext_vector_type(8))) short s16x8;

__device__ __forceinline__ void gload_lds16(const __hip_bfloat16* g, void* l) {
    __builtin_amdgcn_global_load_lds(
        (const __attribute__((address_space(1))) void*)g,
        (__attribute__((address_space(3))) void*)l,
        16, 0, 0);
}

// ---------------- fused prep kernel (one launch, three block ranges) --------
#define XBLKS 16384
#define WBLKS 2048

__global__ __launch_bounds__(256) void prep_all(
    const float* __restrict__ x, const float* __restrict__ weights,
    const float* __restrict__ W, const float* __restrict__ b,
    const float* __restrict__ a_scales, const float* __restrict__ w_scales,
    __hip_bfloat16* __restrict__ xq, __hip_bfloat16* __restrict__ wq,
    float* __restrict__ bm)
{
    const int blk = blockIdx.x;
    if (blk < XBLKS) {
        float A0 = 0.f, A1 = 0.f;
        #pragma unroll
        for (int k = 0; k < 16; ++k) {
            float w = weights[k];
            if (((k >> 1) & 1) == 0) A0 += w; else A1 += w;
        }
        const float s0 = a_scales[0], s1 = a_scales[1];
        const float r0 = 1.f / s0, r1 = 1.f / s1;

        size_t idx = ((size_t)blk * 256 + threadIdx.x) * 8;
        const f32x4* xv = (const f32x4*)(x + idx);
        f32x4 v0 = xv[0], v1 = xv[1];
        float vals[8] = {v0.x, v0.y, v0.z, v0.w, v1.x, v1.y, v1.z, v1.w};

        union { s16x8 v; __hip_bfloat16 h[8]; } u;
        #pragma unroll
        for (int j = 0; j < 8; ++j) {
            float q0 = rintf(fminf(fmaxf(vals[j] * r0, -8.f),   7.f)) * s0;
            float q1 = rintf(fminf(fmaxf(vals[j] * r1, -128.f), 127.f)) * s1;
            u.h[j] = __float2bfloat16(A0 * q0 + A1 * q1);
        }
        *(s16x8*)(xq + idx) = u.v;
    } else if (blk < XBLKS + WBLKS) {
        float c00 = weights[0] + weights[2]  + weights[4]  + weights[6];
        float c01 = weights[1] + weights[3]  + weights[5]  + weights[7];
        float c10 = weights[8] + weights[10] + weights[12] + weights[14];
        float c11 = weights[9] + weights[11] + weights[13] + weights[15];

        const float s0 = w_scales[0], s1 = w_scales[1];
        const float r0 = 1.f / s0, r1 = 1.f / s1;

        size_t idx = ((size_t)(blk - XBLKS) * 256 + threadIdx.x) * 8;
        const int o = (int)(idx >> 11);
        const int c = (int)(idx & 2047);
        const bool inner = (o < 1024) && (c < 1024);
        const float k0 = inner ? (c00 + c10) : c10;
        const float k1 = inner ? (c01 + c11) : c11;

        const f32x4* wv = (const f32x4*)(W + idx);
        f32x4 v0 = wv[0], v1 = wv[1];
        float vals[8] = {v0.x, v0.y, v0.z, v0.w, v1.x, v1.y, v1.z, v1.w};

        union { s16x8 v; __hip_bfloat16 h[8]; } u;
        #pragma unroll
        for (int j = 0; j < 8; ++j) {
            float q0 = rintf(fminf(fmaxf(vals[j] * r0, -8.f),   7.f)) * s0;
            float q1 = rintf(fminf(fmaxf(vals[j] * r1, -128.f), 127.f)) * s1;
            u.h[j] = __float2bfloat16(k0 * q0 + k1 * q1);
        }
        *(s16x8*)(wq + idx) = u.v;
    } else {
        int o = (blk - XBLKS - WBLKS) * 256 + threadIdx.x;
        if (o < NDIM) {
            float S1 = 0.f, S0 = 0.f;
            #pragma unroll
            for (int k = 0; k < 8; ++k)  S0 += weights[k];
            #pragma unroll
            for (int k = 8; k < 16; ++k) S1 += weights[k];
            bm[o] = b[o] * ((o < 1024) ? (S0 + S1) : S1);
        }
    }
}

// ---------------- GEMM: R16 champion K-loop (256x256, 8 waves, ring-5,
// 1 barrier / 2 chunks, register-frugal, wave de-phasing) + NEW epilogue:
// after the K-loop the ring LDS is dead scratch; each wave transposes its
// acc through a private 4.35KB region (row stride 68 floats: write banks
// 2-way = free) and stores C as float4 NONTEMPORAL, each instruction
// covering 4 rows x 256B fully-contiguous segments (vs 64B scalar before,
// 1/4 the store instructions, no L2 pollution). ----

#define NCH 64           // K chunks of 32
#define ASLOT 16384      // bytes per slot plane (256 rows x 64 B)
#define BREG  81920      // B region base (5 A slots first); total 163840 B

#define MFMA(a, b, c) __builtin_amdgcn_mfma_f32_16x16x32_bf16((a), (b), (c), 0, 0, 0)

#define STAGE(KG, T)                                                         \
    gload_lds16(As0 + (KG) * 32, lds + (T) * ASLOT + ldoff);                 \
    gload_lds16(As1 + (KG) * 32, lds + (T) * ASLOT + 8192 + ldoff);          \
    gload_lds16(Bs0 + (KG) * 32, lds + BREG + (T) * ASLOT + ldoff);          \
    gload_lds16(Bs1 + (KG) * 32, lds + BREG + (T) * ASLOT + 8192 + ldoff);

// One step = chunks (c0=slot S0, c1=slot S1); stage kg->T0, kg+1->T1.
// wm=0 waves compute c0 then c1; wm=1 waves c1 then c0 (SIMD de-phasing).
#define STEP(S0, S1, T0, T1)                                                 \
  {                                                                          \
    asm volatile("" ::: "memory");                                           \
    const char* pF  = lds + (wm ? (S1) : (S0)) * ASLOT;          /* 1st */   \
    const char* pFB = pF + BREG;                                             \
    const char* pS  = lds + (wm ? (S0) : (S1)) * ASLOT;          /* 2nd */   \
    const char* pSB = pS + BREG;                                             \
    _Pragma("unroll")                                                        \
    for (int m_ = 0; m_ < 8; ++m_)                                           \
      af[m_] = *(const s16x8*)(pF + aoff + m_ * 1024);                       \
    _Pragma("unroll")                                                        \
    for (int n_ = 0; n_ < 4; ++n_)                                           \
      bf0[n_] = *(const s16x8*)(pFB + boff + n_ * 1024);                     \
    STAGE(kg, T0);                                                           \
    __builtin_amdgcn_s_setprio(1);                                           \
    _Pragma("unroll")                                                        \
    for (int m_ = 0; m_ < 8; ++m_) {    /* 1st-chunk MFMAs; af reload */     \
      acc[m_][0] = MFMA(af[m_], bf0[0], acc[m_][0]);                         \
      acc[m_][1] = MFMA(af[m_], bf0[1], acc[m_][1]);                         \
      acc[m_][2] = MFMA(af[m_], bf0[2], acc[m_][2]);                         \
      acc[m_][3] = MFMA(af[m_], bf0[3], acc[m_][3]);                         \
      af[m_] = *(const s16x8*)(pS + aoff + m_ * 1024);                       \
    }                                                                        \
    __builtin_amdgcn_s_setprio(0);                                           \
    _Pragma("unroll")                                                        \
    for (int n_ = 0; n_ < 4; ++n_)                                           \
      bf1[n_] = *(const s16x8*)(pSB + boff + n_ * 1024);                     \
    STAGE((kg + 1) & (NCH - 1), T1);                                         \
    __builtin_amdgcn_s_setprio(1);                                           \
    _Pragma("unroll")                                                        \
    for (int m_ = 0; m_ < 8; ++m_) {    /* 2nd-chunk MFMAs */                \
      acc[m_][0] = MFMA(af[m_], bf1[0], acc[m_][0]);                         \
      acc[m_][1] = MFMA(af[m_], bf1[1], acc[m_][1]);                         \
      acc[m_][2] = MFMA(af[m_], bf1[2], acc[m_][2]);                         \
      acc[m_][3] = MFMA(af[m_], bf1[3], acc[m_][3]);                         \
    }                                                                        \
    __builtin_amdgcn_s_setprio(0);                                           \
    kg = (kg + 2) & (NCH - 1);                                               \
    asm volatile("s_waitcnt vmcnt(4)" ::: "memory");                         \
    __builtin_amdgcn_s_barrier();                                            \
  }

__global__ __launch_bounds__(512, 2) void gemm256(
    const __hip_bfloat16* __restrict__ A,
    const __hip_bfloat16* __restrict__ B,
    const float* __restrict__ bias,
    float* __restrict__ C)
{
    __shared__ char lds[10 * ASLOT];   // 163840 B = 160 KiB (full CU LDS)

    const int tid  = threadIdx.x;
    const int lane = tid & 63;
    const int wid  = tid >> 6;    // 0..7
    const int wm   = wid >> 2;    // 0..1  (M half; SIMD i hosts wid i, i+4)
    const int wn   = wid & 3;     // 0..3  (N quarter)

    // T1 (measured FETCH ~104 MB): XCD = bid%8 owns 8 row-panels x 8 cols.
    const int bid  = blockIdx.x;
    const int swz  = (bid & 7) * 64 + (bid >> 3);
    const int brow = (swz >> 3) * 256;
    const int bcol = (swz & 7) * 256;

    // ---- staging: linear LDS dest, pre-swizzled global source (T2) ----
    const int csw = (tid & 3) ^ ((tid >> 3) & 3);
    const __hip_bfloat16* As0 = A + (size_t)(brow + (tid >> 2)) * KDIM + csw * 8;
    const __hip_bfloat16* As1 = As0 + (size_t)128 * KDIM;
    const __hip_bfloat16* Bs0 = B + (size_t)(bcol + (tid >> 2)) * KDIM + csw * 8;
    const __hip_bfloat16* Bs1 = Bs0 + (size_t)128 * KDIM;
    const int ldoff = tid * 16;

    // ---- fragment-read constants (swizzle inverse; lane-constant XOR) ----
    const int fr  = lane & 15;
    const int l16 = lane >> 4;
    const int xr  = (l16 ^ ((fr >> 1) & 3)) * 16;
    const int aoff = (wm * 128 + fr) * 64 + xr;
    const int boff = (wn * 64  + fr) * 64 + xr;

    f32x4 acc[8][4];
    #pragma unroll
    for (int m = 0; m < 8; ++m)
        #pragma unroll
        for (int n = 0; n < 4; ++n)
            acc[m][n] = (f32x4){0.f, 0.f, 0.f, 0.f};

    s16x8 af[8], bf0[4], bf1[4];
    int kg = 3;   // next chunk to stage

    // ---- prologue: stage chunks 0,1,2 -> slots 0,1,2; gate chunks 0,1 ----
    #pragma unroll
    for (int q = 0; q < 3; ++q) { STAGE(q, q); }
    asm volatile("s_waitcnt vmcnt(4)" ::: "memory");  // chunks 0,1 landed
    __builtin_amdgcn_s_barrier();

    // 32 steps (64 chunks): slot pattern period 5 steps; 6 cycles + 2 tail.
    #pragma unroll 1
    for (int it = 0; it < 6; ++it) {
        STEP(0, 1, 3, 4);   // s%5==0
        STEP(2, 3, 0, 1);   // s%5==1
        STEP(4, 0, 2, 3);   // s%5==2
        STEP(1, 2, 4, 0);   // s%5==3
        STEP(3, 4, 1, 2);   // s%5==4
    }
    STEP(0, 1, 3, 4);       // step 30 (chunks 60,61)
    STEP(2, 3, 0, 1);       // step 31 (chunks 62,63; wrap stages dead)
    asm volatile("s_waitcnt vmcnt(0) lgkmcnt(0)" ::: "memory");
    __builtin_amdgcn_s_barrier();   // all waves done reading ring -> scratch OK

    // ---- epilogue: per-wave LDS transpose -> float4 nontemporal stores ----
    // scratch: wave-private 17*256B region, row stride 68 floats (write
    // banks 2-way = free). MFMA C/D: col = lane&15, row = (lane>>4)*4 + j.
    float* scr = (float*)lds + wid * 1088;     // 1088 = 16 rows * 68
    const int crow_b = brow + wm * 128;
    const int ccol_b = bcol + wn * 64;
    float bv[4];
    #pragma unroll
    for (int n = 0; n < 4; ++n) bv[n] = bias[ccol_b + n * 16 + fr];

    #pragma unroll
    for (int m = 0; m < 8; ++m) {
        #pragma unroll
        for (int n = 0; n < 4; ++n)
            #pragma unroll
            for (int j = 0; j < 4; ++j)
                scr[(l16 * 4 + j) * 68 + n * 16 + fr] = acc[m][n][j] + bv[n];
        asm volatile("" ::: "memory");
        #pragma unroll
        for (int q = 0; q < 4; ++q) {
            // row group q*4 + l16, cols fr*4..fr*4+3 -> 16 lanes = 256B/row
            f32x4 v = *(const f32x4*)(scr + (q * 4 + l16) * 68 + fr * 4);
            float* dst = C + (size_t)(crow_b + m * 16 + q * 4 + l16) * NDIM
                       + ccol_b + fr * 4;
            __builtin_nontemporal_store(v, (f32x4*)dst);
        }
        asm volatile("" ::: "memory");   // reads done before next m overwrite
    }
}

// ---------------- launcher ----------------

extern "C" void kernel_launch(void* const* d_in, const int* in_sizes, int n_in,
                              void* d_out, int out_size, void* d_ws, size_t ws_size,
                              hipStream_t stream) {
    const float* x        = (const float*)d_in[0];  // [4,4096,2048]
    const float* weights  = (const float*)d_in[1];  // [16]
    const float* W        = (const float*)d_in[2];  // [2048,2048]
    const float* b        = (const float*)d_in[3];  // [2048]
    const float* a_scales = (const float*)d_in[4];  // [2]
    const float* w_scales = (const float*)d_in[5];  // [2]
    float* out = (float*)d_out;

    __hip_bfloat16* xq = (__hip_bfloat16*)d_ws;                            // 67108864 B
    __hip_bfloat16* wq = (__hip_bfloat16*)((char*)d_ws + 67108864);        //  8388608 B
    float*          bm = (float*)((char*)d_ws + 67108864 + 8388608);       //     8192 B

    prep_all<<<dim3(XBLKS + WBLKS + 8), dim3(256), 0, stream>>>(
        x, weights, W, b, a_scales, w_scales, xq, wq, bm);
    gemm256<<<dim3((MDIM / 256) * (NDIM / 256)), dim3(512), 0, stream>>>(xq, wq, bm, out);
}